// Round 3
// baseline (146.768 us; speedup 1.0000x reference)
//
#include <hip/hip_runtime.h>

#define KK 27

typedef short bf16x8 __attribute__((ext_vector_type(8)));   // 8 bf16 in 4 VGPRs
typedef float f32x4  __attribute__((ext_vector_type(4)));

__device__ inline unsigned short f2bf(float f) {            // RNE fp32 -> bf16
    unsigned u = __float_as_uint(f);
    unsigned r = u + 0x7fffu + ((u >> 16) & 1u);
    return (unsigned short)(r >> 16);
}

// ---- Kernel 1 (fused prep): blocks [0,nxblk) transpose+cast x; blocks [nxblk, nxblk+27) prep W ----
// x [32][N] fp32 -> xTb [N+1][32] bf16 (row N is an all-zero row used by out-of-range lanes)
// weight [27][cin=32][cout=32] fp32 -> wTb [27][cout=32][cin=32] bf16
// block nxblk (k==0) additionally zeroes the striped BN accumulator tot[32*64]
// (safe: conv_k launches after prep_k completes, stream-ordered).
__global__ __launch_bounds__(256) void prep_k(const float* __restrict__ in,
                                              const float* __restrict__ w,
                                              unsigned short* __restrict__ xTb,
                                              unsigned short* __restrict__ wTb,
                                              float* __restrict__ tot,
                                              int N, int nxblk) {
    __shared__ float tile[32][33];
    const int b = blockIdx.x;
    if (b < nxblk) {
        int n0 = b * 32;
        int tx = threadIdx.x & 31;
        int ty = threadIdx.x >> 5;  // 0..7
#pragma unroll
        for (int c = ty; c < 32; c += 8) {
            int n = n0 + tx;
            tile[c][tx] = (n < N) ? in[(long)c * N + n] : 0.f;
        }
        __syncthreads();
#pragma unroll
        for (int nn = ty; nn < 32; nn += 8) {
            int n = n0 + nn;
            if (n < N) xTb[(long)n * 32 + tx] = f2bf(tile[tx][nn]);
        }
        if (b == 0 && threadIdx.x < 32) xTb[(long)N * 32 + threadIdx.x] = 0;  // zero row
    } else {
        int k = b - nxblk;
        for (int i = threadIdx.x; i < 1024; i += 256) {
            int cin = i >> 5, cout = i & 31;
            wTb[k * 1024 + cout * 32 + cin] = f2bf(w[k * 1024 + cin * 32 + cout]);
        }
        if (k == 0) {
            for (int i = threadIdx.x; i < 32 * 64; i += 256) tot[i] = 0.f;
        }
    }
}

// ---- Kernel 2: MFMA conv + BN striped atomics ----
// 4 INDEPENDENT waves per 256-thread block; wave w owns 32 nodes (2 gather streams,
// round-0 inner loop verbatim). No __syncthreads anywhere: each wave uses its own
// LDS slice ct[w] (intra-wave LDS ordering is lgkmcnt, compiler-inserted).
// Multi-wave blocks lift the workgroup-slot occupancy cap that limited 1-wave blocks.
// Invalid lanes (node >= N) gather the all-zero row N of xTb.
__global__ __launch_bounds__(256, 4) void conv_k(const unsigned short* __restrict__ xTb,
                                                 const int* __restrict__ neigh,
                                                 const unsigned short* __restrict__ wTb,
                                                 float* __restrict__ y,    // [32][N]
                                                 float* __restrict__ tot,  // [32][64] striped
                                                 int N) {
    __shared__ float ct[4][32][33];    // per-wave private transpose slices

    const int tid  = threadIdx.x;
    const int L    = tid & 63;
    const int w    = tid >> 6;         // 0..3, independent waves
    const int r16  = L & 15;
    const int quad = L >> 4;           // 0..3
    const int base = blockIdx.x * 128 + w * 32;
    const int n0 = base + r16;
    const int n1 = base + 16 + r16;
    const bool v0 = (n0 < N), v1 = (n1 < N);
    const long nb0 = (long)(v0 ? n0 : 0) * KK;
    const long nb1 = (long)(v1 ? n1 : 0) * KK;

    f32x4 acc00 = {0.f, 0.f, 0.f, 0.f};
    f32x4 acc01 = acc00, acc10 = acc00, acc11 = acc00;

    int ia = v0 ? neigh[nb0] : N;
    int ib = v1 ? neigh[nb1] : N;
    int ja = v0 ? neigh[nb0 + 1] : N;
    int jb = v1 ? neigh[nb1 + 1] : N;

    bf16x8 a0 = *(const bf16x8*)(xTb + (long)ia * 32 + quad * 8);
    bf16x8 a1 = *(const bf16x8*)(xTb + (long)ib * 32 + quad * 8);
    bf16x8 b0 = *(const bf16x8*)(wTb + r16 * 32 + quad * 8);
    bf16x8 b1 = *(const bf16x8*)(wTb + (16 + r16) * 32 + quad * 8);

#pragma unroll 1
    for (int k = 0; k < KK; ++k) {
        bf16x8 na0, na1, pb0, pb1;
        if (k < KK - 1) {
            na0 = *(const bf16x8*)(xTb + (long)ja * 32 + quad * 8);
            na1 = *(const bf16x8*)(xTb + (long)jb * 32 + quad * 8);
            const unsigned short* wn = wTb + (k + 1) * 1024;
            pb0 = *(const bf16x8*)(wn + r16 * 32 + quad * 8);
            pb1 = *(const bf16x8*)(wn + (16 + r16) * 32 + quad * 8);
            int kk = (k + 2 < KK) ? (k + 2) : (KK - 1);
            ja = v0 ? neigh[nb0 + kk] : N;
            jb = v1 ? neigh[nb1 + kk] : N;
        }

        acc00 = __builtin_amdgcn_mfma_f32_16x16x32_bf16(a0, b0, acc00, 0, 0, 0);
        acc01 = __builtin_amdgcn_mfma_f32_16x16x32_bf16(a0, b1, acc01, 0, 0, 0);
        acc10 = __builtin_amdgcn_mfma_f32_16x16x32_bf16(a1, b0, acc10, 0, 0, 0);
        acc11 = __builtin_amdgcn_mfma_f32_16x16x32_bf16(a1, b1, acc11, 0, 0, 0);

        if (k < KK - 1) {
            a0 = na0;
            a1 = na1;
            b0 = pb0;
            b1 = pb1;
        }
    }

    // BN partials: sum over this wave's 32 nodes.
    // C/D layout: cout = r16 (acc*0) / 16+r16 (acc*1), node = quad*4 + reg (+16 tile).
    float s0 = 0.f, q0 = 0.f, s1 = 0.f, q1 = 0.f;
#pragma unroll
    for (int r = 0; r < 4; ++r) {
        s0 += acc00[r] + acc10[r];
        q0 += acc00[r] * acc00[r] + acc10[r] * acc10[r];
        s1 += acc01[r] + acc11[r];
        q1 += acc01[r] * acc01[r] + acc11[r] * acc11[r];
    }
#pragma unroll
    for (int off = 16; off < 64; off <<= 1) {   // reduce across quads (nodes)
        s0 += __shfl_xor(s0, off, 64);
        q0 += __shfl_xor(q0, off, 64);
        s1 += __shfl_xor(s1, off, 64);
        q1 += __shfl_xor(q1, off, 64);
    }
    const int stripe = (blockIdx.x * 4 + w) & 31;   // 32-way striping kills contention
    if (L < 16) {
        float* tb = tot + stripe * 64;
        atomicAdd(&tb[L],      s0);
        atomicAdd(&tb[L + 16], s1);
        atomicAdd(&tb[L + 32], q0);
        atomicAdd(&tb[L + 48], q1);
    }

    // per-wave LDS transpose -> coalesced y stores ([cout][node], 32 contiguous nodes)
#pragma unroll
    for (int r = 0; r < 4; ++r) {
        ct[w][quad * 4 + r][r16]           = acc00[r];
        ct[w][quad * 4 + r][16 + r16]      = acc01[r];
        ct[w][16 + quad * 4 + r][r16]      = acc10[r];
        ct[w][16 + quad * 4 + r][16 + r16] = acc11[r];
    }
    // no barrier: ct[w] is written and read only by wave w (lgkmcnt ordering)
    const int node = L & 31;
    const int half = L >> 5;
    const int gn = base + node;
    if (gn < N) {
#pragma unroll
        for (int i = 0; i < 16; ++i) {
            const int cout = i * 2 + half;
            y[(long)cout * N + gn] = ct[w][node][cout];
        }
    }
}

// ---- Kernel 3: normalize y in place (stripe-reduce + stats finalize fused) ----
__global__ __launch_bounds__(256) void norm_k(float* __restrict__ y,
                                              const float* __restrict__ tot,
                                              const float* __restrict__ gamma,
                                              const float* __restrict__ beta, int N) {
    const int d = blockIdx.y;
    float sm = 0.f, sq = 0.f;
#pragma unroll
    for (int s = 0; s < 32; ++s) {              // reduce the 32 stripes (L2-hot, 8KB)
        sm += tot[s * 64 + d];
        sq += tot[s * 64 + 32 + d];
    }
    const float mean = sm / (float)N;
    const float var  = sq / (float)N - mean * mean;
    const float sc   = gamma[d] * rsqrtf(var + 1e-3f);
    const float sh   = beta[d] - mean * sc;

    int i = blockIdx.x * blockDim.x + threadIdx.x;
    int base = i * 4;
    if (base + 3 < N) {
        float4* p = (float4*)(y + (long)d * N + base);
        float4 v = *p;
        v.x = fmaf(v.x, sc, sh);
        v.y = fmaf(v.y, sc, sh);
        v.z = fmaf(v.z, sc, sh);
        v.w = fmaf(v.w, sc, sh);
        *p = v;
    } else if (base < N) {
        for (int t = base; t < N; ++t) y[(long)d * N + t] = fmaf(y[(long)d * N + t], sc, sh);
    }
}

// ---- launcher ----
extern "C" void kernel_launch(void* const* d_in, const int* in_sizes, int n_in,
                              void* d_out, int out_size, void* d_ws, size_t ws_size,
                              hipStream_t stream) {
    const float* data_in = (const float*)d_in[0];
    const int*   neigh   = (const int*)d_in[1];
    const float* weight  = (const float*)d_in[2];
    const float* gamma   = (const float*)d_in[3];
    const float* beta    = (const float*)d_in[4];
    float* out = (float*)d_out;

    const int N = in_sizes[1] / KK;
    const int nxblk   = (N + 31) / 32;    // x-prep blocks
    const int nblk128 = (N + 127) / 128;  // 128 nodes per 4-wave conv block

    char* ws = (char*)d_ws;
    unsigned short* xTb = (unsigned short*)ws;                            // (N+1)*32 bf16
    unsigned short* wTb = (unsigned short*)(ws + (size_t)(N + 1) * 64);   // 27*1024 bf16
    float* tot = (float*)(ws + (size_t)(N + 1) * 64 + 55296);             // 32*64 floats

    prep_k<<<nxblk + KK, 256, 0, stream>>>(data_in, weight, xTb, wTb, tot, N, nxblk);
    conv_k<<<nblk128, 256, 0, stream>>>(xTb, neigh, wTb, out, tot, N);
    dim3 ngrid(((N + 3) / 4 + 255) / 256, 32);
    norm_k<<<ngrid, 256, 0, stream>>>(out, tot, gamma, beta, N);
}